// Round 17
// baseline (50.371 us; speedup 1.0000x reference)
//
#include <hip/hip_runtime.h>
#include <math.h>

#define N 8192
#define D 256
#define TILE 128
#define NB (N / TILE)              // 64 panels
#define NBLK (NB * (NB + 1) / 2)   // 2080 upper-triangular blocks

typedef _Float16 half8 __attribute__((ext_vector_type(8)));
typedef float f32x4 __attribute__((ext_vector_type(4)));

constexpr float MARGIN = 0.5f;
constexpr float EPS_F  = 1e-10f;

// Blocked fragment-native layout for x16t (halves):
//   offset(row, k) = (row>>4)*4096 + (k>>3)*128 + (row&15)*8 + (k&7)
// A fragment load (16 rows x 8 halves x 4 k-groups) = 1024 contiguous bytes.

// ---------------------------------------------------------------------------
// Fused prologue (one dispatch, 512 blocks x 256 thr):
//   all blocks  : fp32 -> fp16 BLOCKED layout + exact fp32 row sq-norms
//   blocks 0-15 : label detect/normalize + per-block 64-bin histogram slice
//   blocks 16-47: zero the 8 per-XCD partial sum arrays (16N floats)
//   block 48    : zero out[0]
// ---------------------------------------------------------------------------
__global__ void prep_kernel(const float* __restrict__ xs,
                            const int* __restrict__ ys_raw,
                            _Float16* __restrict__ x16t, float* __restrict__ sq,
                            int* __restrict__ lbl, int* __restrict__ hist16,
                            float* __restrict__ sums, float* __restrict__ out) {
    const int tid = threadIdx.x;
    const int rb  = blockIdx.x;

    // ---- convert + sq (every block handles a 16-row tile) ----
    {
        const int r   = tid >> 4;
        const int c16 = tid & 15;
        const int row = rb * 16 + r;

        const float4* src = (const float4*)xs + (size_t)row * (D / 4) + c16 * 4;
        const float4 v0 = src[0], v1 = src[1], v2 = src[2], v3 = src[3];

        half8 h0 = { (_Float16)v0.x, (_Float16)v0.y, (_Float16)v0.z, (_Float16)v0.w,
                     (_Float16)v1.x, (_Float16)v1.y, (_Float16)v1.z, (_Float16)v1.w };
        half8 h1 = { (_Float16)v2.x, (_Float16)v2.y, (_Float16)v2.z, (_Float16)v2.w,
                     (_Float16)v3.x, (_Float16)v3.y, (_Float16)v3.z, (_Float16)v3.w };

        _Float16* dst = x16t + (size_t)rb * 4096 + (c16 * 2) * 128 + r * 8;
        *(half8*)dst         = h0;
        *(half8*)(dst + 128) = h1;

        float s = v0.x*v0.x + v0.y*v0.y + v0.z*v0.z + v0.w*v0.w
                + v1.x*v1.x + v1.y*v1.y + v1.z*v1.z + v1.w*v1.w
                + v2.x*v2.x + v2.y*v2.y + v2.z*v2.z + v2.w*v2.w
                + v3.x*v3.x + v3.y*v3.y + v3.z*v3.z + v3.w*v3.w;
#pragma unroll
        for (int off = 1; off < 16; off <<= 1) s += __shfl_xor(s, off);
        if (c16 == 0) sq[row] = s;
    }

    // ---- labels + histogram slice (blocks 0-15, 512 labels each) ----
    if (rb < 16) {
        __shared__ int bad_s;
        __shared__ int lh[64];
        const int base = rb * 512;
        if (tid == 0) bad_s = 0;
        if (tid < 64) lh[tid] = 0;
        __syncthreads();
        int bad = 0;
        for (int i = tid; i < 512; i += 256) bad |= (ys_raw[2 * (base + i) + 1] != 0);
        if (bad) atomicOr(&bad_s, 1);
        __syncthreads();
        const bool is64 = (bad_s == 0);
        for (int i = tid; i < 512; i += 256) {
            const int v = is64 ? ys_raw[2 * (base + i)] : ys_raw[base + i];
            lbl[base + i] = v;
            atomicAdd(&lh[v & 63], 1);
        }
        __syncthreads();
        if (tid < 64) hist16[rb * 64 + tid] = lh[tid];   // exclusive slice
    }

    // ---- zero per-XCD partials (blocks 16-47: 32 blocks x 4096 floats = 16N) ----
    if (rb >= 16 && rb < 48) {
        const int base = (rb - 16) * 4096;
#pragma unroll
        for (int k = 0; k < 16; ++k) sums[base + k * 256 + tid] = 0.f;
    }
    if (rb == 48 && tid == 0) out[0] = 0.f;
}

// ---------------------------------------------------------------------------
// Barrier-free symmetric MFMA pair kernel (r5 k-loop + r7 lean epilogue):
// fragments loaded directly from the blocked global layout (1 KB coalesced
// loads, L1/L2-resident), depth-1 register double-buffer, NO LDS, NO
// barriers -> waves fully independent (pure TLP latency hiding).
// 2080 upper-tri blocks, 4 waves (2x2 of 64x64). Per-XCD partial atomics.
// ---------------------------------------------------------------------------
__global__ __launch_bounds__(256) void pair_kernel(
    const _Float16* __restrict__ x16t, const int* __restrict__ lbl,
    const float* __restrict__ sq,
    float* __restrict__ sum_same8, float* __restrict__ sum_all8) {

    // ---- XCD-bijective swizzle (2080 % 8 == 0 -> exact chunking) ----
    const int xcd = blockIdx.x & 7;         // == XCD under round-robin dispatch
    const int t   = xcd * (NBLK / 8) + blockIdx.x / 8;
    float* __restrict__ sum_same = sum_same8 + (size_t)xcd * N;
    float* __restrict__ sum_all  = sum_all8  + (size_t)xcd * N;

    // ---- decode upper-triangular block index: t -> (bi, bj), bi<=bj ----
    int bj = (int)((sqrtf(8.f * (float)t + 1.f) - 1.f) * 0.5f);
    while ((bj + 1) * (bj + 2) / 2 <= t) ++bj;
    while (bj * (bj + 1) / 2 > t) --bj;
    const int bi    = t - bj * (bj + 1) / 2;
    const bool diag = (bi == bj);
    const int i0 = bi * TILE;
    const int j0 = bj * TILE;

    const int tid  = threadIdx.x;
    const int w    = tid >> 6;
    const int lane = tid & 63;
    const int wm   = w >> 1;
    const int wn   = w & 1;
    const int cl   = lane & 15;
    const int g    = lane >> 4;

    f32x4 acc[4][4];
#pragma unroll
    for (int a = 0; a < 4; ++a)
#pragma unroll
        for (int b = 0; b < 4; ++b) acc[a][b] = (f32x4){0.f, 0.f, 0.f, 0.f};

    // per-lane fragment base: row-tile (i0>>4 + wm*4 + mf), k-chunk g, row cl
    const _Float16* pa = x16t + (size_t)((i0 >> 4) + wm * 4) * 4096 + g * 128 + cl * 8;
    const _Float16* pb = x16t + (size_t)((j0 >> 4) + wn * 4) * 4096 + g * 128 + cl * 8;

    half8 af[2][4], bf[2][4];
#pragma unroll
    for (int mf = 0; mf < 4; ++mf) {
        af[0][mf] = *(const half8*)(pa + mf * 4096);
        bf[0][mf] = *(const half8*)(pb + mf * 4096);
    }

    const int colbase = j0 + wn * 64;
    float sqj_[4];
    int   yj_[4];

#pragma unroll
    for (int t8 = 0; t8 < 8; ++t8) {           // fully unrolled -> static [t8&1]
        if (t8 < 7) {
            const int koff = (t8 + 1) * 512;   // 32 k per iter = 512 halves
#pragma unroll
            for (int mf = 0; mf < 4; ++mf) {
                af[(t8 + 1) & 1][mf] = *(const half8*)(pa + mf * 4096 + koff);
                bf[(t8 + 1) & 1][mf] = *(const half8*)(pb + mf * 4096 + koff);
            }
        }
        // last iter: issue epilogue operand loads; latency hides under MFMAs
        if (t8 == 7) {
#pragma unroll
            for (int nf = 0; nf < 4; ++nf) {
                const int c = colbase + nf * 16 + cl;
                sqj_[nf] = sq[c];
                yj_[nf]  = lbl[c];
            }
        }

        __builtin_amdgcn_s_setprio(1);
#pragma unroll
        for (int mf = 0; mf < 4; ++mf)
#pragma unroll
            for (int nf = 0; nf < 4; ++nf)
                acc[mf][nf] = __builtin_amdgcn_mfma_f32_16x16x32_f16(
                    af[t8 & 1][mf], bf[t8 & 1][nf], acc[mf][nf], 0, 0, 0);
        __builtin_amdgcn_s_setprio(0);
    }

    // ---- epilogue (r7/r10-verified, two batches of 8 rows) ----
    // C layout (m89): col = lane&15 (j-local), row = (lane>>4)*4 + reg (i-local)
    const int rowbase = i0 + wm * 64;

    float cs_all[4], cs_same[4];      // col sums (over i) -> rows of panel bj
#pragma unroll
    for (int nf = 0; nf < 4; ++nf) { cs_all[nf] = 0.f; cs_same[nf] = 0.f; }

#pragma unroll
    for (int b = 0; b < 2; ++b) {
        float rs_all[8], rs_same[8];
#pragma unroll
        for (int e = 0; e < 8; ++e) { rs_all[e] = 0.f; rs_same[e] = 0.f; }

#pragma unroll
        for (int mh = 0; mh < 2; ++mh) {
            const int mf = 2 * b + mh;
#pragma unroll
            for (int r = 0; r < 4; ++r) {
                const int row   = rowbase + mf * 16 + g * 4 + r;
                const float sqi = sq[row];
                const int   yi  = lbl[row];
#pragma unroll
                for (int nf = 0; nf < 4; ++nf) {
                    float d2   = sqi + sqj_[nf] - 2.f * acc[mf][nf][r];
                    float dist = __builtin_amdgcn_sqrtf(fmaxf(d2, EPS_F));
                    if (diag) {
                        const int col = colbase + nf * 16 + cl;
                        if (row == col) dist = 1e-5f;   // exact diagonal sqrt(EPS)
                    }
                    const float dm = (yi == yj_[nf]) ? dist : 0.f;
                    cs_all[nf] += dist;
                    cs_same[nf] += dm;
                    rs_all[mh * 4 + r] += dist;
                    rs_same[mh * 4 + r] += dm;
                }
            }
        }

        // row direction (off-diag only): value-split 8 values over 16 lanes,
        // closing mask-1 stage completes the 16-lane sum; even-cl lanes own
        // entry e = cl>>1.
        if (!diag) {
#define RSTEP(h, mask, bit)                                                     \
            {                                                                   \
                const bool hi = (cl >> (bit)) & 1;                              \
                _Pragma("unroll")                                               \
                for (int j = 0; j < (h); ++j) {                                 \
                    float sa_ = hi ? rs_all[j] : rs_all[j + (h)];               \
                    float ka_ = hi ? rs_all[j + (h)] : rs_all[j];               \
                    rs_all[j] = ka_ + __shfl_xor(sa_, (mask));                  \
                    float ss_ = hi ? rs_same[j] : rs_same[j + (h)];             \
                    float ks_ = hi ? rs_same[j + (h)] : rs_same[j];             \
                    rs_same[j] = ks_ + __shfl_xor(ss_, (mask));                 \
                }                                                               \
            }
            RSTEP(4, 8, 3)
            RSTEP(2, 4, 2)
            RSTEP(1, 2, 1)
#undef RSTEP
            rs_all[0]  += __shfl_xor(rs_all[0], 1);   // closing stage (mask 1)
            rs_same[0] += __shfl_xor(rs_same[0], 1);

            const int e    = cl >> 1;
            const int rrow = rowbase + (2 * b + (e >> 2)) * 16 + g * 4 + (e & 3);
            if (!(cl & 1)) {
                atomicAdd(&sum_all[rrow],  rs_all[0]);
                atomicAdd(&sum_same[rrow], rs_same[0]);
            }
        }
    }

    // ---- col direction: value-split reduce 4 values over 4 g-lanes
    {
        const bool hi1 = (g >> 1) & 1;
#pragma unroll
        for (int j = 0; j < 2; ++j) {
            float sa_ = hi1 ? cs_all[j] : cs_all[j + 2];
            float ka_ = hi1 ? cs_all[j + 2] : cs_all[j];
            cs_all[j] = ka_ + __shfl_xor(sa_, 32);
            float ss_ = hi1 ? cs_same[j] : cs_same[j + 2];
            float ks_ = hi1 ? cs_same[j + 2] : cs_same[j];
            cs_same[j] = ks_ + __shfl_xor(ss_, 32);
        }
        const bool hi0 = g & 1;
        {
            float sa_ = hi0 ? cs_all[0] : cs_all[1];
            float ka_ = hi0 ? cs_all[1] : cs_all[0];
            cs_all[0] = ka_ + __shfl_xor(sa_, 16);
            float ss_ = hi0 ? cs_same[0] : cs_same[1];
            float ks_ = hi0 ? cs_same[1] : cs_same[0];
            cs_same[0] = ks_ + __shfl_xor(ss_, 16);
        }
        const int ccol = colbase + g * 16 + cl;
        atomicAdd(&sum_all[ccol],  cs_all[0]);
        atomicAdd(&sum_same[ccol], cs_same[0]);
    }
}

// ---------------------------------------------------------------------------
// Finalize: 32 blocks x 256 thr, one row per thread. Sums the 8 per-XCD
// partials; histogram from the 16 precomputed slices.
// ---------------------------------------------------------------------------
__global__ void finalize_kernel(const float* __restrict__ sum_same8,
                                const float* __restrict__ sum_all8,
                                const int* __restrict__ lbl,
                                const int* __restrict__ hist16,
                                float* __restrict__ out) {
    __shared__ int lh[64];
    __shared__ float wsums[4];
    const int tid = threadIdx.x;
    if (tid < 64) {
        int h = 0;
#pragma unroll
        for (int b = 0; b < 16; ++b) h += hist16[b * 64 + tid];
        lh[tid] = h;
    }
    __syncthreads();

    const int row = blockIdx.x * 256 + tid;
    float ss = 0.f, sa = 0.f;
#pragma unroll
    for (int x = 0; x < 8; ++x) {
        ss += sum_same8[(size_t)x * N + row];
        sa += sum_all8[(size_t)x * N + row];
    }

    const float cnt = (float)lh[lbl[row]];
    const float ap  = ss / cnt;
    const float an  = (sa - ss) / ((float)N - cnt);
    float local = fmaxf(ap - an + MARGIN, 0.f);

#pragma unroll
    for (int off = 32; off > 0; off >>= 1) local += __shfl_down(local, off);
    const int lane = tid & 63, wave = tid >> 6;
    if (lane == 0) wsums[wave] = local;
    __syncthreads();
    if (tid == 0)
        atomicAdd(out, (wsums[0] + wsums[1] + wsums[2] + wsums[3]) / (float)N);
}

// ---------------------------------------------------------------------------
extern "C" void kernel_launch(void* const* d_in, const int* in_sizes, int n_in,
                              void* d_out, int out_size, void* d_ws, size_t ws_size,
                              hipStream_t stream) {
    const float* xs     = (const float*)d_in[0];
    const int*   ys_raw = (const int*)d_in[1];

    float* ws        = (float*)d_ws;
    float* sum_same8 = ws;                         // [8][N]
    float* sum_all8  = ws + 8 * N;                 // [8][N]
    float* sqv       = ws + 16 * N;                // [N]
    int*   lbl       = (int*)(ws + 17 * N);        // [N]
    int*   hist16    = (int*)(ws + 18 * N);        // [16*64]
    _Float16* x16t   = (_Float16*)(ws + 18 * N + 1024);  // [N*D] blocked fp16 (4 MB)

    prep_kernel<<<N / 16, 256, 0, stream>>>(xs, ys_raw, x16t, sqv, lbl, hist16,
                                            sum_same8, (float*)d_out);

    pair_kernel<<<NBLK, 256, 0, stream>>>(x16t, lbl, sqv, sum_same8, sum_all8);

    finalize_kernel<<<32, 256, 0, stream>>>(sum_same8, sum_all8, lbl, hist16,
                                            (float*)d_out);
}